// Round 14
// baseline (240.367 us; speedup 1.0000x reference)
//
#include <hip/hip_runtime.h>

// GCN layer: out = sum_r segment_sum(vals_r * inp[src_r], dst_r) @ W_r
// Round 18: round-17's dbuf gather was correct but __launch_bounds__(256,4)
// capped VGPR at 128 -> the twin buffers SPILLED TO SCRATCH (WRITE 29->138MB,
// FETCH 77->167MB at reported VGPR=64). Fix: launch_bounds(256,3) — grid is
// 782 blocks (~3/CU) so real occupancy is unchanged, VGPR cap rises to ~170
// and the pipeline buffers live in registers. No other change.
// N=50000, R=8, E=100000, IN=OUT=128.

constexpr int IN  = 128;
constexpr int OUT = 128;
constexpr int LDK = 136;     // legacy bf16 LDS row pad (fallback kernels)
constexpr int NPB = 64;      // nodes per bin
constexpr int LDKB = 136;    // bf16 A-tile row stride (elems), 272 B
constexpr int CAPMAX = 256;  // max entries per (rel,bin) cell (<= blockDim)
constexpr int NBINS_MAX = 1024;
constexpr int EPB = 2048;    // edges per fill block (392 fill blocks)

typedef __attribute__((ext_vector_type(8))) short bf16x8;
typedef __attribute__((ext_vector_type(4))) float f32x4;

__device__ inline unsigned short f2bf(float f) {
    unsigned int u = __float_as_uint(f);
    u += 0x7fffu + ((u >> 16) & 1u);          // RNE
    return (unsigned short)(u >> 16);
}
__device__ inline float bflo(unsigned int u) { return __uint_as_float(u << 16); }
__device__ inline float bfhi(unsigned int u) { return __uint_as_float(u & 0xffff0000u); }
__device__ inline unsigned int pack2bf(float a, float b) {
    return (unsigned)f2bf(a) | ((unsigned)f2bf(b) << 16);
}
// HW packed f32->bf16 (RNE), lo=a hi=b. No builtin on gfx950; asm per guide.
__device__ inline unsigned int cvtpk_bf16(float a, float b) {
    unsigned int r;
    asm("v_cvt_pk_bf16_f32 %0, %1, %2" : "=v"(r) : "v"(a), "v"(b));
    return r;
}

// ---------------- converts (standalone, fallback paths) ---------------------
__global__ __launch_bounds__(256) void conv_inp_kernel(
    const float* __restrict__ x, unsigned short* __restrict__ y, int n8)
{
    const int i = blockIdx.x * 256 + threadIdx.x;
    if (i >= n8) return;
    const float4 a = ((const float4*)x)[i * 2];
    const float4 b = ((const float4*)x)[i * 2 + 1];
    uint4 o;
    o.x = pack2bf(a.x, a.y);
    o.y = pack2bf(a.z, a.w);
    o.z = pack2bf(b.x, b.y);
    o.w = pack2bf(b.z, b.w);
    ((uint4*)y)[i] = o;
}

// Wt[r][n][k] = W[r][k][n], bf16
__global__ __launch_bounds__(256) void conv_w_kernel(
    const float* __restrict__ w, unsigned short* __restrict__ wt, int total)
{
    const int t = blockIdx.x * 256 + threadIdx.x;
    if (t >= total) return;
    const int r = t >> 14, rem = t & 16383;
    const int n = rem >> 7, k = rem & 127;
    wt[t] = f2bf(w[(r << 14) + (k << 7) + n]);
}

// ---------------- prep: fill blocks FIRST, then conv blocks -----------------
// Fill: 2048 edges of one relation per block. LDS histogram by bin, one
// global atomicAdd per non-empty bin, place at gbase+localpos.
// entry: .x = ((dst&63)<<19) | src   (needs n_nodes < 2^19)
__global__ __launch_bounds__(256) void prep_kernel(
    const int* __restrict__ src, const int* __restrict__ dst,
    const float* __restrict__ vals, int* __restrict__ bin_cnt,
    int2* __restrict__ binned, int4* __restrict__ spill,
    int* __restrict__ spill_cnt,
    int n_edges, int n_nodes, int nbins, int cap, int spill_max,
    int fgx, int nF,
    const float* __restrict__ x, unsigned short* __restrict__ y, int n8, int nbI,
    const float* __restrict__ w, unsigned short* __restrict__ wtb, int wtot)
{
    __shared__ int hist[NBINS_MAX];
    __shared__ int gbase[NBINS_MAX];

    const int bid = blockIdx.x;
    const int tid = threadIdx.x;

    if (bid >= nF) {
        const int cb = bid - nF;
        if (cb < nbI) {
            const int i = cb * 256 + tid;
            if (i >= n8) return;
            const float4 a = ((const float4*)x)[i * 2];
            const float4 b = ((const float4*)x)[i * 2 + 1];
            uint4 o;
            o.x = pack2bf(a.x, a.y);
            o.y = pack2bf(a.z, a.w);
            o.z = pack2bf(b.x, b.y);
            o.w = pack2bf(b.z, b.w);
            ((uint4*)y)[i] = o;
        } else {
            const int t = (cb - nbI) * 256 + tid;
            if (t >= wtot) return;
            const int r = t >> 14, rem = t & 16383;
            const int n = rem >> 7, k = rem & 127;
            wtb[t] = f2bf(w[(r << 14) + (k << 7) + n]);
        }
        return;
    }

    // ---- fill ----
    const int rel = bid / fgx;
    const int e0 = (bid - rel * fgx) * EPB;
    const size_t base_e = (size_t)rel * n_edges;

    for (int b = tid; b < nbins; b += 256) hist[b] = 0;
    __syncthreads();

    // pass 1: count
    #pragma unroll
    for (int j = 0; j < EPB / 256; ++j) {
        const int e = e0 + j * 256 + tid;
        if (e < n_edges) atomicAdd(&hist[dst[base_e + e] >> 6], 1);
    }
    __syncthreads();

    // allocate one global range per non-empty bin; reset hist for pass 2
    for (int b = tid; b < nbins; b += 256) {
        const int c = hist[b];
        gbase[b] = c ? atomicAdd(&bin_cnt[rel * nbins + b], c) : 0;
        hist[b] = 0;
    }
    __syncthreads();

    // pass 2: place (edge reads L2-hot)
    #pragma unroll
    for (int j = 0; j < EPB / 256; ++j) {
        const int e = e0 + j * 256 + tid;
        if (e >= n_edges) continue;
        const int d = dst[base_e + e];
        const int s = src[base_e + e];
        const float v = vals[base_e + e];
        const int b = d >> 6;
        const int lp = atomicAdd(&hist[b], 1);
        const int pos = gbase[b] + lp;
        if (pos < cap) {
            binned[(size_t)(rel * nbins + b) * cap + pos] =
                make_int2(((d & 63) << 19) | s, __float_as_int(v));
        } else {
            const int sp = atomicAdd(spill_cnt, 1);
            if (sp < spill_max)
                spill[sp] = make_int4(d, (rel << 19) | s, __float_as_int(v), 0);
        }
    }
}

// ---------------- per-bin: reg-held sort + dbuf gather + bf16 flush + MFMA --
#define LOADB(EB, UB, IBASE)                                                 \
    _Pragma("unroll")                                                        \
    for (int k = 0; k < 8; ++k) {                                            \
        const int idx_ = (IBASE) + k;                                        \
        EB[k] = (idx_ < end) ? sorted[idx_] : make_int2(gend << 19, 0);      \
    }                                                                        \
    _Pragma("unroll")                                                        \
    for (int k = 0; k < 8; ++k)                                              \
        UB[k] = ((const unsigned int*)(                                      \
            inpb + (size_t)(EB[k].x & 0x7ffff) * IN))[lane];

#define PROCB(EB, UB)                                                        \
    _Pragma("unroll")                                                        \
    for (int k = 0; k < 8; ++k) {                                            \
        const int ln_ = (EB[k].x >> 19) & 63;                                \
        if (ln_ != cur) {                                                    \
            *(unsigned int*)&Ab[cur * LDKB + lane * 2] = cvtpk_bf16(a0, a1); \
            a0 = 0.f; a1 = 0.f; cur = ln_;                                   \
        }                                                                    \
        const float v_ = __int_as_float(EB[k].y);                            \
        a0 += v_ * bflo(UB[k]); a1 += v_ * bfhi(UB[k]);                      \
    }

__global__ __launch_bounds__(256, 3) void bin_gemm_kernel(
    const unsigned short* __restrict__ inpb,
    const unsigned short* __restrict__ wt,
    const int2* __restrict__ binned, const int* __restrict__ bin_cnt,
    float* __restrict__ out, int n_nodes, int nbins, int cap, int n_rel)
{
    __shared__ unsigned short Ab[NPB * LDKB];   // 17.4 KB bf16 A-tile
    __shared__ int2 sorted[CAPMAX];             // 2 KB
    __shared__ int lcnt[NPB];
    __shared__ int loff[NPB + 1];
    __shared__ int lcur[NPB];
    __shared__ int relcnt[8];

    const int bin = blockIdx.x;
    const int tid = threadIdx.x;
    const int wave = tid >> 6, lane = tid & 63;
    const int m = lane & 15, q = lane >> 4;

    if (tid < n_rel) {
        int c = bin_cnt[tid * nbins + bin];
        relcnt[tid] = c > cap ? cap : c;
    }
    if (tid < NPB) { lcnt[tid] = 0; lcur[tid] = 0; }
    __syncthreads();

    int2 ecur = make_int2((NPB - 1) << 19, 0);
    if (tid < relcnt[0])
        ecur = binned[(size_t)bin * cap + tid];

    f32x4 acc[4][2];
    #pragma unroll
    for (int mt = 0; mt < 4; ++mt) {
        acc[mt][0] = (f32x4){0.f, 0.f, 0.f, 0.f};
        acc[mt][1] = (f32x4){0.f, 0.f, 0.f, 0.f};
    }

    for (int r = 0; r < n_rel; ++r) {
        const int cnt = relcnt[r];

        // W-frag loads issued early: sort+gather hides their L2 latency.
        const unsigned short* wtr = wt + ((size_t)r * OUT + wave * 32) * IN;
        bf16x8 bfrag[2][4];
        #pragma unroll
        for (int nt = 0; nt < 2; ++nt)
            #pragma unroll
            for (int ks = 0; ks < 4; ++ks)
                bfrag[nt][ks] = *(const bf16x8*)(
                    wtr + (size_t)(nt * 16 + m) * IN + ks * 32 + q * 8);

        // R1: zero Ab (linear, conflict-free) + histogram from register
        {
            uint4* A4 = (uint4*)Ab;
            #pragma unroll
            for (int j = 0; j < (NPB * LDKB / 8 + 255) / 256; ++j) {
                const int idx = j * 256 + tid;
                if (idx < NPB * LDKB / 8)
                    A4[idx] = make_uint4(0u, 0u, 0u, 0u);
            }
        }
        if (tid < cnt) atomicAdd(&lcnt[(ecur.x >> 19) & (NPB - 1)], 1);
        __syncthreads();

        // R2: exclusive scan over 64 groups (wave 0)
        if (tid < NPB) {
            const int v = lcnt[tid];
            int incl = v;
            #pragma unroll
            for (int off = 1; off < NPB; off <<= 1) {
                const int t = __shfl_up(incl, off, NPB);
                if (tid >= off) incl += t;
            }
            loff[tid] = incl - v;
            if (tid == NPB - 1) loff[NPB] = incl;
        }
        __syncthreads();

        // R3: place (entry from register); re-zero lcnt for next rel
        if (tid < cnt) {
            const int g = (ecur.x >> 19) & (NPB - 1);
            const int pos = atomicAdd(&lcur[g], 1);
            sorted[loff[g] + pos] = ecur;
        }
        if (tid < NPB) lcnt[tid] = 0;
        __syncthreads();

        // R4: prefetch next rel's entry; DOUBLE-BUFFERED sorted gather
        // (batch i+1 rows in flight while accumulating batch i).
        int2 enext = make_int2((NPB - 1) << 19, 0);
        if (r + 1 < n_rel && tid < relcnt[r + 1])
            enext = binned[(size_t)((r + 1) * nbins + bin) * cap + tid];

        {
            const int g0 = wave * 16;                // 16 nodes per wave
            const int gend = g0 + 15;
            const int start = loff[g0];
            const int end = loff[g0 + 16];
            int cur = g0;
            float a0 = 0.f, a1 = 0.f;
            int2 eA[8], eB[8]; unsigned int uA[8], uB[8];
            int i = start;
            if (i < end) {
                LOADB(eA, uA, i);
                i += 8;
                for (;;) {
                    if (i < end) {
                        LOADB(eB, uB, i);
                        i += 8;
                        PROCB(eA, uA);
                    } else { PROCB(eA, uA); break; }
                    if (i < end) {
                        LOADB(eA, uA, i);
                        i += 8;
                        PROCB(eB, uB);
                    } else { PROCB(eB, uB); break; }
                }
            }
            *(unsigned int*)&Ab[cur * LDKB + lane * 2] = cvtpk_bf16(a0, a1);
        }
        if (tid < NPB) lcur[tid] = 0;
        __syncthreads();

        // R5: MFMA — a-frags read directly as bf16x8 from Ab
        #pragma unroll
        for (int ks = 0; ks < 4; ++ks) {
            bf16x8 a[4];
            #pragma unroll
            for (int mt = 0; mt < 4; ++mt)
                a[mt] = *(const bf16x8*)&Ab[(mt * 16 + m) * LDKB
                                            + ks * 32 + q * 8];
            #pragma unroll
            for (int mt = 0; mt < 4; ++mt) {
                acc[mt][0] = __builtin_amdgcn_mfma_f32_16x16x32_bf16(
                    a[mt], bfrag[0][ks], acc[mt][0], 0, 0, 0);
                acc[mt][1] = __builtin_amdgcn_mfma_f32_16x16x32_bf16(
                    a[mt], bfrag[1][ks], acc[mt][1], 0, 0, 0);
            }
        }
        ecur = enext;
        __syncthreads();   // Ab reads done before next rel's zero
    }

    // epilogue
    const int row0 = bin * NPB;
    #pragma unroll
    for (int mt = 0; mt < 4; ++mt) {
        #pragma unroll
        for (int rg = 0; rg < 4; ++rg) {
            const int row = row0 + mt * 16 + q * 4 + rg;
            if (row < n_nodes) {
                float* op = out + (size_t)row * OUT + wave * 32 + m;
                op[0]  = acc[mt][0][rg];
                op[16] = acc[mt][1][rg];
            }
        }
    }
}

// ---------------- spill cleanup: out[d] += val * (inp[src] @ W[rel]) --------
__global__ __launch_bounds__(256) void spill_w_kernel(
    const unsigned short* __restrict__ inpb,
    const unsigned short* __restrict__ wt,
    const int4* __restrict__ spill, const int* __restrict__ spill_cnt,
    float* __restrict__ out, int spill_max)
{
    int n = *spill_cnt;
    if (n > spill_max) n = spill_max;
    const int w = (blockIdx.x * 256 + threadIdx.x) >> 6;
    const int lane = threadIdx.x & 63;
    const int nw = gridDim.x * 4;
    for (int i = w; i < n; i += nw) {
        const int4 s = spill[i];
        const int d = s.x;
        const int rel = s.y >> 19, srcrow = s.y & 0x7ffff;
        const float v = __int_as_float(s.z);
        const unsigned short* irow = inpb + (size_t)srcrow * IN;
        #pragma unroll
        for (int cc = 0; cc < 2; ++cc) {
            const int col = lane * 2 + cc;
            const unsigned short* wrow = wt + ((size_t)rel * OUT + col) * IN;
            float acc = 0.f;
            for (int k8 = 0; k8 < IN; k8 += 8) {
                const uint4 iw = *(const uint4*)(irow + k8);
                const uint4 ww = *(const uint4*)(wrow + k8);
                acc += bflo(iw.x)*bflo(ww.x) + bfhi(iw.x)*bfhi(ww.x)
                     + bflo(iw.y)*bflo(ww.y) + bfhi(iw.y)*bfhi(ww.y)
                     + bflo(iw.z)*bflo(ww.z) + bfhi(iw.z)*bfhi(ww.z)
                     + bflo(iw.w)*bflo(ww.w) + bfhi(iw.w)*bfhi(ww.w);
            }
            __hip_atomic_fetch_add(out + (size_t)d * OUT + col, v * acc,
                                   __ATOMIC_RELAXED, __HIP_MEMORY_SCOPE_AGENT);
        }
    }
}

// ================= legacy fallback machinery (h-based) ======================
__global__ __launch_bounds__(256) void mfma_gemm(
    const unsigned short* __restrict__ inpb,
    const unsigned short* __restrict__ wt,
    unsigned short* __restrict__ h, int rel_base, int n_nodes)
{
    __shared__ unsigned short As[128 * LDK];

    const int rel = rel_base + blockIdx.y;
    const int row0 = blockIdx.x * 128;
    const int tid = threadIdx.x;
    const int wave = tid >> 6, lane = tid & 63;
    const int m = lane & 15, q = lane >> 4;

    {
        const int r = tid >> 1;
        const int half = (tid & 1) * 64;
        const int grow = row0 + r;
        const uint4* gp = (const uint4*)(inpb + (size_t)grow * IN + half);
        uint4* lp = (uint4*)&As[r * LDK + half];
        #pragma unroll
        for (int i = 0; i < 8; ++i) {
            uint4 v = make_uint4(0u, 0u, 0u, 0u);
            if (grow < n_nodes) v = gp[i];
            lp[i] = v;
        }
    }

    bf16x8 bfrag[2][4];
    {
        const unsigned short* wtr = wt + ((size_t)rel * OUT + wave * 32) * IN;
        #pragma unroll
        for (int nt = 0; nt < 2; ++nt)
            #pragma unroll
            for (int ks = 0; ks < 4; ++ks)
                bfrag[nt][ks] = *(const bf16x8*)(
                    wtr + (size_t)(nt * 16 + m) * IN + ks * 32 + q * 8);
    }

    __syncthreads();

    f32x4 acc[8][2];
    #pragma unroll
    for (int mt = 0; mt < 8; ++mt)
        #pragma unroll
        for (int nt = 0; nt < 2; ++nt)
            acc[mt][nt] = (f32x4){0.f, 0.f, 0.f, 0.f};

    #pragma unroll
    for (int ks = 0; ks < 4; ++ks) {
        bf16x8 a[8];
        #pragma unroll
        for (int mt = 0; mt < 8; ++mt)
            a[mt] = *(const bf16x8*)&As[(mt * 16 + m) * LDK + ks * 32 + q * 8];
        #pragma unroll
        for (int mt = 0; mt < 8; ++mt) {
            acc[mt][0] = __builtin_amdgcn_mfma_f32_16x16x32_bf16(
                a[mt], bfrag[0][ks], acc[mt][0], 0, 0, 0);
            acc[mt][1] = __builtin_amdgcn_mfma_f32_16x16x32_bf16(
                a[mt], bfrag[1][ks], acc[mt][1], 0, 0, 0);
        }
    }

    unsigned short* hrel = h + (size_t)blockIdx.y * n_nodes * OUT;
    #pragma unroll
    for (int mt = 0; mt < 8; ++mt) {
        #pragma unroll
        for (int rg = 0; rg < 4; ++rg) {
            const int row = row0 + mt * 16 + q * 4 + rg;
            if (row < n_nodes) {
                unsigned short* hp = hrel + (size_t)row * OUT + wave * 32 + m;
                hp[0]  = f2bf(acc[mt][0][rg]);
                hp[16] = f2bf(acc[mt][1][rg]);
            }
        }
    }
}

__global__ __launch_bounds__(256) void fill_kernel(
    const int* __restrict__ src, const int* __restrict__ dst,
    const float* __restrict__ vals, int* __restrict__ counts,
    int2* __restrict__ bucket, int4* __restrict__ spill,
    int* __restrict__ spill_cnt, int n_edges, int n_nodes,
    int cap, int spill_max)
{
    const int e = blockIdx.x * 256 + threadIdx.x;
    if (e >= n_edges) return;
    const size_t g = (size_t)blockIdx.y * n_edges + e;
    const int d = dst[g];
    const int enc = blockIdx.y * n_nodes + src[g];
    const int pos = atomicAdd(&counts[d], 1);
    if (pos < cap) {
        bucket[(size_t)d * cap + pos] = make_int2(enc, __float_as_int(vals[g]));
    } else {
        const int sp = atomicAdd(spill_cnt, 1);
        if (sp < spill_max)
            spill[sp] = make_int4(d, enc, __float_as_int(vals[g]), 0);
    }
}

__global__ __launch_bounds__(256) void gather_kernel(
    const unsigned short* __restrict__ h, const int2* __restrict__ bucket,
    const int* __restrict__ counts, float* __restrict__ out,
    int n_nodes, int cap, int accum)
{
    const int node = blockIdx.x * 8 + (threadIdx.x >> 5);
    const int lane = threadIdx.x & 31;
    if (node >= n_nodes) return;
    int cnt = counts[node];
    if (cnt > cap) cnt = cap;
    const int2* __restrict__ b = bucket + (size_t)node * cap;
    float4* __restrict__ op = (float4*)(out + (size_t)node * OUT);

    float4 acc = accum ? op[lane] : make_float4(0.f, 0.f, 0.f, 0.f);
    int j = 0;
    for (; j + 4 <= cnt; j += 4) {
        const int2 r0 = b[j], r1 = b[j + 1], r2 = b[j + 2], r3 = b[j + 3];
        const uint2 h0 = ((const uint2*)(h + (size_t)r0.x * OUT))[lane];
        const uint2 h1 = ((const uint2*)(h + (size_t)r1.x * OUT))[lane];
        const uint2 h2 = ((const uint2*)(h + (size_t)r2.x * OUT))[lane];
        const uint2 h3 = ((const uint2*)(h + (size_t)r3.x * OUT))[lane];
        const float v0 = __int_as_float(r0.y), v1 = __int_as_float(r1.y);
        const float v2 = __int_as_float(r2.y), v3 = __int_as_float(r3.y);
        acc.x += v0*bflo(h0.x) + v1*bflo(h1.x) + v2*bflo(h2.x) + v3*bflo(h3.x);
        acc.y += v0*bfhi(h0.x) + v1*bfhi(h1.x) + v2*bfhi(h2.x) + v3*bfhi(h3.x);
        acc.z += v0*bflo(h0.y) + v1*bflo(h1.y) + v2*bflo(h2.y) + v3*bflo(h3.y);
        acc.w += v0*bfhi(h0.y) + v1*bfhi(h1.y) + v2*bfhi(h2.y) + v3*bfhi(h3.y);
    }
    for (; j < cnt; ++j) {
        const int2 r0 = b[j];
        const float v = __int_as_float(r0.y);
        const uint2 hv = ((const uint2*)(h + (size_t)r0.x * OUT))[lane];
        acc.x += v * bflo(hv.x); acc.y += v * bfhi(hv.x);
        acc.z += v * bflo(hv.y); acc.w += v * bfhi(hv.y);
    }
    op[lane] = acc;
}

__global__ __launch_bounds__(256) void spill_kernel(
    const unsigned short* __restrict__ h, const int4* __restrict__ spill,
    const int* __restrict__ spill_cnt, float* __restrict__ out, int spill_max)
{
    int n = *spill_cnt;
    if (n > spill_max) n = spill_max;
    const int w = (blockIdx.x * 256 + threadIdx.x) >> 6;
    const int lane = threadIdx.x & 63;
    const int nw = gridDim.x * 4;
    for (int i = w; i < n; i += nw) {
        const int4 s = spill[i];
        const float v = __int_as_float(s.z);
        const unsigned int u = ((const unsigned int*)(h + (size_t)s.y * OUT))[lane];
        float* __restrict__ orow = out + (size_t)s.x * OUT;
        __hip_atomic_fetch_add(orow + lane * 2,     v * bflo(u),
                               __ATOMIC_RELAXED, __HIP_MEMORY_SCOPE_AGENT);
        __hip_atomic_fetch_add(orow + lane * 2 + 1, v * bfhi(u),
                               __ATOMIC_RELAXED, __HIP_MEMORY_SCOPE_AGENT);
    }
}

__global__ __launch_bounds__(256) void scatter_kernel(
    const unsigned short* __restrict__ h, const int* __restrict__ src,
    const int* __restrict__ dst, const float* __restrict__ vals,
    float* __restrict__ out, int n_edges)
{
    const int e = blockIdx.x * 8 + (threadIdx.x >> 5);
    if (e >= n_edges) return;
    const int lane = threadIdx.x & 31;
    const int s = src[e];
    const int d = dst[e];
    const float v = vals[e];
    const unsigned int* __restrict__ hrow =
        (const unsigned int*)(h + (size_t)s * OUT);
    float* __restrict__ orow = out + (size_t)d * OUT;
    #pragma unroll
    for (int kk = 0; kk < 2; ++kk) {
        const int jj = lane + kk * 32;
        const unsigned int u = hrow[jj];
        __hip_atomic_fetch_add(orow + jj * 2,     v * bflo(u),
                               __ATOMIC_RELAXED, __HIP_MEMORY_SCOPE_AGENT);
        __hip_atomic_fetch_add(orow + jj * 2 + 1, v * bfhi(u),
                               __ATOMIC_RELAXED, __HIP_MEMORY_SCOPE_AGENT);
    }
}

extern "C" void kernel_launch(void* const* d_in, const int* in_sizes, int n_in,
                              void* d_out, int out_size, void* d_ws, size_t ws_size,
                              hipStream_t stream) {
    const float* inp     = (const float*)d_in[0];
    const int*   src     = (const int*)  d_in[1];
    const int*   dst     = (const int*)  d_in[2];
    const float* vals    = (const float*)d_in[3];
    const float* weights = (const float*)d_in[4];
    float* out = (float*)d_out;

    const int n_nodes = in_sizes[0] / IN;            // 50000
    const int n_rel   = in_sizes[4] / (IN * OUT);    // 8
    const int n_edges = in_sizes[1] / n_rel;         // 100000

    auto align_up = [](size_t x) { return (x + 255) & ~(size_t)255; };
    const int SPILL_MAX = 65536;
    const size_t sz_inpb   = align_up((size_t)n_nodes * IN * 2);
    const size_t sz_wt     = align_up((size_t)n_rel * IN * OUT * 2);
    const size_t sz_spill  = align_up((size_t)SPILL_MAX * 16);

    const int conv_n8 = n_nodes * IN / 8;
    const int wt_tot  = n_rel * IN * OUT;
    const int gemm_gx = (n_nodes + 127) / 128;
    const int gath_gx = (n_nodes + 7) / 8;
    const int fill_gx = (n_edges + 255) / 256;
    const int nbins   = (n_nodes + NPB - 1) / NPB;   // 782

    // ---- primary path: destarved fused fill + dbuf-gather bin GEMM ----
    if (n_rel <= 8 && n_nodes < (1 << 19) && nbins <= NBINS_MAX) {
        const size_t ncells  = (size_t)n_rel * nbins;
        const size_t sz_bcnt = align_up((ncells + 1) * 4);
        int cap = 0;
        const int caps[] = {256, 192, 128};
        for (int c : caps) {
            const size_t sz_binned = align_up(ncells * c * 8);
            if (sz_inpb + sz_wt + sz_bcnt + sz_spill + sz_binned <= ws_size) {
                cap = c; break;
            }
        }
        if (cap > 0) {
            const size_t sz_binned = align_up(ncells * cap * 8);
            char* p = (char*)d_ws;
            unsigned short* inpb = (unsigned short*)p;  p += sz_inpb;
            unsigned short* wtb  = (unsigned short*)p;  p += sz_wt;
            int*   bin_cnt = (int*)p;   p += sz_bcnt;
            int4*  spill   = (int4*)p;  p += sz_spill;
            int2*  binned  = (int2*)p;  p += sz_binned;
            int*   spill_cnt = bin_cnt + ncells;

            const int nbI = (conv_n8 + 255) / 256;
            const int nbW = (wt_tot + 255) / 256;
            const int fgx = (n_edges + EPB - 1) / EPB;
            const int nF  = fgx * n_rel;

            hipMemsetAsync(bin_cnt, 0, (ncells + 1) * 4, stream);
            prep_kernel<<<nF + nbI + nbW, 256, 0, stream>>>(
                src, dst, vals, bin_cnt, binned, spill, spill_cnt,
                n_edges, n_nodes, nbins, cap, SPILL_MAX, fgx, nF,
                inp, inpb, conv_n8, nbI, weights, wtb, wt_tot);
            bin_gemm_kernel<<<nbins, 256, 0, stream>>>(
                inpb, wtb, binned, bin_cnt, out, n_nodes, nbins, cap, n_rel);
            spill_w_kernel<<<128, 256, 0, stream>>>(
                inpb, wtb, spill, spill_cnt, out, SPILL_MAX);
            return;
        }
    }

    const size_t sz_counts = align_up((size_t)(n_nodes + 1) * 4);
    const size_t fixed = sz_inpb + sz_wt + sz_counts + sz_spill;

    // ---- legacy full path: per-node buckets + h GEMM + gather ----
    {
        const size_t sz_h = (size_t)n_rel * n_nodes * OUT * 2;
        int cap = 0;
        const int caps[] = {64, 48, 32, 24, 20};
        for (int c : caps) {
            if (fixed + sz_h + align_up((size_t)n_nodes * c * 8) <= ws_size) {
                cap = c; break;
            }
        }
        if (cap > 0) {
            char* p = (char*)d_ws;
            unsigned short* inpb = (unsigned short*)p;  p += sz_inpb;
            unsigned short* wtb  = (unsigned short*)p;  p += sz_wt;
            int*   counts = (int*)p;    p += sz_counts;
            int4*  spill  = (int4*)p;   p += sz_spill;
            unsigned short* h = (unsigned short*)p;     p += sz_h;
            int2*  bucket = (int2*)p;
            int*   spill_cnt = counts + n_nodes;

            conv_inp_kernel<<<(conv_n8 + 255) / 256, 256, 0, stream>>>(
                inp, inpb, conv_n8);
            conv_w_kernel<<<(wt_tot + 255) / 256, 256, 0, stream>>>(
                weights, wtb, wt_tot);
            hipMemsetAsync(counts, 0, (size_t)(n_nodes + 1) * 4, stream);
            dim3 fg(fill_gx, n_rel);
            fill_kernel<<<fg, 256, 0, stream>>>(src, dst, vals, counts, bucket,
                                                spill, spill_cnt, n_edges,
                                                n_nodes, cap, SPILL_MAX);
            dim3 gg(gemm_gx, n_rel);
            mfma_gemm<<<gg, 256, 0, stream>>>(inpb, wtb, h, 0, n_nodes);
            gather_kernel<<<gath_gx, 256, 0, stream>>>(h, bucket, counts, out,
                                                       n_nodes, cap, 0);
            spill_kernel<<<128, 256, 0, stream>>>(h, spill, spill_cnt, out,
                                                  SPILL_MAX);
            return;
        }
    }

    // ---- last resort: per-relation gemm + atomic scatter ----
    {
        char* p = (char*)d_ws;
        unsigned short* inpb = (unsigned short*)p;  p += sz_inpb;
        unsigned short* wtb  = (unsigned short*)p;  p += sz_wt;
        unsigned short* h = (unsigned short*)p;

        conv_inp_kernel<<<(conv_n8 + 255) / 256, 256, 0, stream>>>(
            inp, inpb, conv_n8);
        conv_w_kernel<<<(wt_tot + 255) / 256, 256, 0, stream>>>(
            weights, wtb, wt_tot);
        hipMemsetAsync(out, 0, (size_t)n_nodes * OUT * 4, stream);
        const int sgx = (n_edges + 7) / 8;
        for (int r = 0; r < n_rel; ++r) {
            const size_t eoff = (size_t)r * n_edges;
            dim3 gg(gemm_gx, 1);
            mfma_gemm<<<gg, 256, 0, stream>>>(inpb, wtb, h, r, n_nodes);
            scatter_kernel<<<sgx, 256, 0, stream>>>(h, src + eoff, dst + eoff,
                                                    vals + eoff, out, n_edges);
        }
    }
}

// Round 15
// 185.061 us; speedup vs baseline: 1.2989x; 1.2989x over previous
//
#include <hip/hip_runtime.h>

// GCN layer: out = sum_r segment_sum(vals_r * inp[src_r], dst_r) @ W_r
// Round 19 = EXACT revert to round-14 (best measured: 185.5 us total,
// bin_gemm 81.8 us). The dbuf-gather line (rounds 17/18) is abandoned:
// with spill it costs 138 MB scratch traffic; without spill the branchy
// batch alternation defeats compiler scheduling (147 us). Round-14's
// simple strided gather + cvt_pk bf16 flush is the verified optimum.
// N=50000, R=8, E=100000, IN=OUT=128.

constexpr int IN  = 128;
constexpr int OUT = 128;
constexpr int LDK = 136;     // legacy bf16 LDS row pad (fallback kernels)
constexpr int NPB = 64;      // nodes per bin
constexpr int LDKB = 136;    // bf16 A-tile row stride (elems), 272 B
constexpr int CAPMAX = 256;  // max entries per (rel,bin) cell (<= blockDim)
constexpr int NBINS_MAX = 1024;
constexpr int EPB = 2048;    // edges per fill block (392 fill blocks)

typedef __attribute__((ext_vector_type(8))) short bf16x8;
typedef __attribute__((ext_vector_type(4))) float f32x4;

__device__ inline unsigned short f2bf(float f) {
    unsigned int u = __float_as_uint(f);
    u += 0x7fffu + ((u >> 16) & 1u);          // RNE
    return (unsigned short)(u >> 16);
}
__device__ inline float bflo(unsigned int u) { return __uint_as_float(u << 16); }
__device__ inline float bfhi(unsigned int u) { return __uint_as_float(u & 0xffff0000u); }
__device__ inline unsigned int pack2bf(float a, float b) {
    return (unsigned)f2bf(a) | ((unsigned)f2bf(b) << 16);
}
// HW packed f32->bf16 (RNE), lo=a hi=b. No builtin on gfx950; asm per guide.
__device__ inline unsigned int cvtpk_bf16(float a, float b) {
    unsigned int r;
    asm("v_cvt_pk_bf16_f32 %0, %1, %2" : "=v"(r) : "v"(a), "v"(b));
    return r;
}

// ---------------- converts (standalone, fallback paths) ---------------------
__global__ __launch_bounds__(256) void conv_inp_kernel(
    const float* __restrict__ x, unsigned short* __restrict__ y, int n8)
{
    const int i = blockIdx.x * 256 + threadIdx.x;
    if (i >= n8) return;
    const float4 a = ((const float4*)x)[i * 2];
    const float4 b = ((const float4*)x)[i * 2 + 1];
    uint4 o;
    o.x = pack2bf(a.x, a.y);
    o.y = pack2bf(a.z, a.w);
    o.z = pack2bf(b.x, b.y);
    o.w = pack2bf(b.z, b.w);
    ((uint4*)y)[i] = o;
}

// Wt[r][n][k] = W[r][k][n], bf16
__global__ __launch_bounds__(256) void conv_w_kernel(
    const float* __restrict__ w, unsigned short* __restrict__ wt, int total)
{
    const int t = blockIdx.x * 256 + threadIdx.x;
    if (t >= total) return;
    const int r = t >> 14, rem = t & 16383;
    const int n = rem >> 7, k = rem & 127;
    wt[t] = f2bf(w[(r << 14) + (k << 7) + n]);
}

// ---------------- prep: fill blocks FIRST, then conv blocks -----------------
// Fill: 2048 edges of one relation per block. LDS histogram by bin, one
// global atomicAdd per non-empty bin, place at gbase+localpos.
// entry: .x = ((dst&63)<<19) | src   (needs n_nodes < 2^19)
__global__ __launch_bounds__(256) void prep_kernel(
    const int* __restrict__ src, const int* __restrict__ dst,
    const float* __restrict__ vals, int* __restrict__ bin_cnt,
    int2* __restrict__ binned, int4* __restrict__ spill,
    int* __restrict__ spill_cnt,
    int n_edges, int n_nodes, int nbins, int cap, int spill_max,
    int fgx, int nF,
    const float* __restrict__ x, unsigned short* __restrict__ y, int n8, int nbI,
    const float* __restrict__ w, unsigned short* __restrict__ wtb, int wtot)
{
    __shared__ int hist[NBINS_MAX];
    __shared__ int gbase[NBINS_MAX];

    const int bid = blockIdx.x;
    const int tid = threadIdx.x;

    if (bid >= nF) {
        const int cb = bid - nF;
        if (cb < nbI) {
            const int i = cb * 256 + tid;
            if (i >= n8) return;
            const float4 a = ((const float4*)x)[i * 2];
            const float4 b = ((const float4*)x)[i * 2 + 1];
            uint4 o;
            o.x = pack2bf(a.x, a.y);
            o.y = pack2bf(a.z, a.w);
            o.z = pack2bf(b.x, b.y);
            o.w = pack2bf(b.z, b.w);
            ((uint4*)y)[i] = o;
        } else {
            const int t = (cb - nbI) * 256 + tid;
            if (t >= wtot) return;
            const int r = t >> 14, rem = t & 16383;
            const int n = rem >> 7, k = rem & 127;
            wtb[t] = f2bf(w[(r << 14) + (k << 7) + n]);
        }
        return;
    }

    // ---- fill ----
    const int rel = bid / fgx;
    const int e0 = (bid - rel * fgx) * EPB;
    const size_t base_e = (size_t)rel * n_edges;

    for (int b = tid; b < nbins; b += 256) hist[b] = 0;
    __syncthreads();

    // pass 1: count
    #pragma unroll
    for (int j = 0; j < EPB / 256; ++j) {
        const int e = e0 + j * 256 + tid;
        if (e < n_edges) atomicAdd(&hist[dst[base_e + e] >> 6], 1);
    }
    __syncthreads();

    // allocate one global range per non-empty bin; reset hist for pass 2
    for (int b = tid; b < nbins; b += 256) {
        const int c = hist[b];
        gbase[b] = c ? atomicAdd(&bin_cnt[rel * nbins + b], c) : 0;
        hist[b] = 0;
    }
    __syncthreads();

    // pass 2: place (edge reads L2-hot)
    #pragma unroll
    for (int j = 0; j < EPB / 256; ++j) {
        const int e = e0 + j * 256 + tid;
        if (e >= n_edges) continue;
        const int d = dst[base_e + e];
        const int s = src[base_e + e];
        const float v = vals[base_e + e];
        const int b = d >> 6;
        const int lp = atomicAdd(&hist[b], 1);
        const int pos = gbase[b] + lp;
        if (pos < cap) {
            binned[(size_t)(rel * nbins + b) * cap + pos] =
                make_int2(((d & 63) << 19) | s, __float_as_int(v));
        } else {
            const int sp = atomicAdd(spill_cnt, 1);
            if (sp < spill_max)
                spill[sp] = make_int4(d, (rel << 19) | s, __float_as_int(v), 0);
        }
    }
}

// ---------------- per-bin: reg-held sort + bf16-flush gather + MFMA ---------
__global__ __launch_bounds__(256, 4) void bin_gemm_kernel(
    const unsigned short* __restrict__ inpb,
    const unsigned short* __restrict__ wt,
    const int2* __restrict__ binned, const int* __restrict__ bin_cnt,
    float* __restrict__ out, int n_nodes, int nbins, int cap, int n_rel)
{
    __shared__ unsigned short Ab[NPB * LDKB];   // 17.4 KB bf16 A-tile
    __shared__ int2 sorted[CAPMAX];             // 2 KB
    __shared__ int lcnt[NPB];
    __shared__ int loff[NPB + 1];
    __shared__ int lcur[NPB];
    __shared__ int relcnt[8];

    const int bin = blockIdx.x;
    const int tid = threadIdx.x;
    const int wave = tid >> 6, lane = tid & 63;
    const int m = lane & 15, q = lane >> 4;

    if (tid < n_rel) {
        int c = bin_cnt[tid * nbins + bin];
        relcnt[tid] = c > cap ? cap : c;
    }
    if (tid < NPB) { lcnt[tid] = 0; lcur[tid] = 0; }
    __syncthreads();

    int2 ecur = make_int2((NPB - 1) << 19, 0);
    if (tid < relcnt[0])
        ecur = binned[(size_t)bin * cap + tid];

    f32x4 acc[4][2];
    #pragma unroll
    for (int mt = 0; mt < 4; ++mt) {
        acc[mt][0] = (f32x4){0.f, 0.f, 0.f, 0.f};
        acc[mt][1] = (f32x4){0.f, 0.f, 0.f, 0.f};
    }

    for (int r = 0; r < n_rel; ++r) {
        const int cnt = relcnt[r];

        // W-frag loads issued early: sort+gather hides their L2 latency.
        const unsigned short* wtr = wt + ((size_t)r * OUT + wave * 32) * IN;
        bf16x8 bfrag[2][4];
        #pragma unroll
        for (int nt = 0; nt < 2; ++nt)
            #pragma unroll
            for (int ks = 0; ks < 4; ++ks)
                bfrag[nt][ks] = *(const bf16x8*)(
                    wtr + (size_t)(nt * 16 + m) * IN + ks * 32 + q * 8);

        // R1: zero Ab (linear, conflict-free) + histogram from register
        {
            uint4* A4 = (uint4*)Ab;
            #pragma unroll
            for (int j = 0; j < (NPB * LDKB / 8 + 255) / 256; ++j) {
                const int idx = j * 256 + tid;
                if (idx < NPB * LDKB / 8)
                    A4[idx] = make_uint4(0u, 0u, 0u, 0u);
            }
        }
        if (tid < cnt) atomicAdd(&lcnt[(ecur.x >> 19) & (NPB - 1)], 1);
        __syncthreads();

        // R2: exclusive scan over 64 groups (wave 0)
        if (tid < NPB) {
            const int v = lcnt[tid];
            int incl = v;
            #pragma unroll
            for (int off = 1; off < NPB; off <<= 1) {
                const int t = __shfl_up(incl, off, NPB);
                if (tid >= off) incl += t;
            }
            loff[tid] = incl - v;
            if (tid == NPB - 1) loff[NPB] = incl;
        }
        __syncthreads();

        // R3: place (entry from register); re-zero lcnt for next rel
        if (tid < cnt) {
            const int g = (ecur.x >> 19) & (NPB - 1);
            const int pos = atomicAdd(&lcur[g], 1);
            sorted[loff[g] + pos] = ecur;
        }
        if (tid < NPB) lcnt[tid] = 0;
        __syncthreads();

        // R4: prefetch next rel's entry; sorted-order gather with DIRECT
        // bf16 flush (v_cvt_pk_bf16_f32, 1 instr)
        int2 enext = make_int2((NPB - 1) << 19, 0);
        if (r + 1 < n_rel && tid < relcnt[r + 1])
            enext = binned[(size_t)((r + 1) * nbins + bin) * cap + tid];

        {
            const int g0 = wave * 16;                // 16 nodes per wave
            const int gend = g0 + 15;
            const int start = loff[g0];
            const int end = loff[g0 + 16];
            int cur = g0;
            float a0 = 0.f, a1 = 0.f;
            for (int i = start; i < end; i += 8) {
                int2 e[8]; unsigned int u[8];
                #pragma unroll
                for (int k = 0; k < 8; ++k) {
                    const int idx = i + k;
                    // dummy = wave's LAST node, v=0: overwrite-safe.
                    e[k] = (idx < end) ? sorted[idx]
                                       : make_int2(gend << 19, 0);
                }
                #pragma unroll
                for (int k = 0; k < 8; ++k)
                    u[k] = ((const unsigned int*)(
                        inpb + (size_t)(e[k].x & 0x7ffff) * IN))[lane];
                #pragma unroll
                for (int k = 0; k < 8; ++k) {
                    const int ln = (e[k].x >> 19) & 63;
                    if (ln != cur) {
                        *(unsigned int*)&Ab[cur * LDKB + lane * 2] =
                            cvtpk_bf16(a0, a1);
                        a0 = 0.f; a1 = 0.f; cur = ln;
                    }
                    const float v = __int_as_float(e[k].y);
                    a0 += v * bflo(u[k]); a1 += v * bfhi(u[k]);
                }
            }
            *(unsigned int*)&Ab[cur * LDKB + lane * 2] = cvtpk_bf16(a0, a1);
        }
        if (tid < NPB) lcur[tid] = 0;
        __syncthreads();

        // R5: MFMA — a-frags read directly as bf16x8 from Ab
        #pragma unroll
        for (int ks = 0; ks < 4; ++ks) {
            bf16x8 a[4];
            #pragma unroll
            for (int mt = 0; mt < 4; ++mt)
                a[mt] = *(const bf16x8*)&Ab[(mt * 16 + m) * LDKB
                                            + ks * 32 + q * 8];
            #pragma unroll
            for (int mt = 0; mt < 4; ++mt) {
                acc[mt][0] = __builtin_amdgcn_mfma_f32_16x16x32_bf16(
                    a[mt], bfrag[0][ks], acc[mt][0], 0, 0, 0);
                acc[mt][1] = __builtin_amdgcn_mfma_f32_16x16x32_bf16(
                    a[mt], bfrag[1][ks], acc[mt][1], 0, 0, 0);
            }
        }
        ecur = enext;
        __syncthreads();   // Ab reads done before next rel's zero
    }

    // epilogue
    const int row0 = bin * NPB;
    #pragma unroll
    for (int mt = 0; mt < 4; ++mt) {
        #pragma unroll
        for (int rg = 0; rg < 4; ++rg) {
            const int row = row0 + mt * 16 + q * 4 + rg;
            if (row < n_nodes) {
                float* op = out + (size_t)row * OUT + wave * 32 + m;
                op[0]  = acc[mt][0][rg];
                op[16] = acc[mt][1][rg];
            }
        }
    }
}

// ---------------- spill cleanup: out[d] += val * (inp[src] @ W[rel]) --------
__global__ __launch_bounds__(256) void spill_w_kernel(
    const unsigned short* __restrict__ inpb,
    const unsigned short* __restrict__ wt,
    const int4* __restrict__ spill, const int* __restrict__ spill_cnt,
    float* __restrict__ out, int spill_max)
{
    int n = *spill_cnt;
    if (n > spill_max) n = spill_max;
    const int w = (blockIdx.x * 256 + threadIdx.x) >> 6;
    const int lane = threadIdx.x & 63;
    const int nw = gridDim.x * 4;
    for (int i = w; i < n; i += nw) {
        const int4 s = spill[i];
        const int d = s.x;
        const int rel = s.y >> 19, srcrow = s.y & 0x7ffff;
        const float v = __int_as_float(s.z);
        const unsigned short* irow = inpb + (size_t)srcrow * IN;
        #pragma unroll
        for (int cc = 0; cc < 2; ++cc) {
            const int col = lane * 2 + cc;
            const unsigned short* wrow = wt + ((size_t)rel * OUT + col) * IN;
            float acc = 0.f;
            for (int k8 = 0; k8 < IN; k8 += 8) {
                const uint4 iw = *(const uint4*)(irow + k8);
                const uint4 ww = *(const uint4*)(wrow + k8);
                acc += bflo(iw.x)*bflo(ww.x) + bfhi(iw.x)*bfhi(ww.x)
                     + bflo(iw.y)*bflo(ww.y) + bfhi(iw.y)*bfhi(ww.y)
                     + bflo(iw.z)*bflo(ww.z) + bfhi(iw.z)*bfhi(ww.z)
                     + bflo(iw.w)*bflo(ww.w) + bfhi(iw.w)*bfhi(ww.w);
            }
            __hip_atomic_fetch_add(out + (size_t)d * OUT + col, v * acc,
                                   __ATOMIC_RELAXED, __HIP_MEMORY_SCOPE_AGENT);
        }
    }
}

// ================= legacy fallback machinery (h-based) ======================
__global__ __launch_bounds__(256) void mfma_gemm(
    const unsigned short* __restrict__ inpb,
    const unsigned short* __restrict__ wt,
    unsigned short* __restrict__ h, int rel_base, int n_nodes)
{
    __shared__ unsigned short As[128 * LDK];

    const int rel = rel_base + blockIdx.y;
    const int row0 = blockIdx.x * 128;
    const int tid = threadIdx.x;
    const int wave = tid >> 6, lane = tid & 63;
    const int m = lane & 15, q = lane >> 4;

    {
        const int r = tid >> 1;
        const int half = (tid & 1) * 64;
        const int grow = row0 + r;
        const uint4* gp = (const uint4*)(inpb + (size_t)grow * IN + half);
        uint4* lp = (uint4*)&As[r * LDK + half];
        #pragma unroll
        for (int i = 0; i < 8; ++i) {
            uint4 v = make_uint4(0u, 0u, 0u, 0u);
            if (grow < n_nodes) v = gp[i];
            lp[i] = v;
        }
    }

    bf16x8 bfrag[2][4];
    {
        const unsigned short* wtr = wt + ((size_t)rel * OUT + wave * 32) * IN;
        #pragma unroll
        for (int nt = 0; nt < 2; ++nt)
            #pragma unroll
            for (int ks = 0; ks < 4; ++ks)
                bfrag[nt][ks] = *(const bf16x8*)(
                    wtr + (size_t)(nt * 16 + m) * IN + ks * 32 + q * 8);
    }

    __syncthreads();

    f32x4 acc[8][2];
    #pragma unroll
    for (int mt = 0; mt < 8; ++mt)
        #pragma unroll
        for (int nt = 0; nt < 2; ++nt)
            acc[mt][nt] = (f32x4){0.f, 0.f, 0.f, 0.f};

    #pragma unroll
    for (int ks = 0; ks < 4; ++ks) {
        bf16x8 a[8];
        #pragma unroll
        for (int mt = 0; mt < 8; ++mt)
            a[mt] = *(const bf16x8*)&As[(mt * 16 + m) * LDK + ks * 32 + q * 8];
        #pragma unroll
        for (int mt = 0; mt < 8; ++mt) {
            acc[mt][0] = __builtin_amdgcn_mfma_f32_16x16x32_bf16(
                a[mt], bfrag[0][ks], acc[mt][0], 0, 0, 0);
            acc[mt][1] = __builtin_amdgcn_mfma_f32_16x16x32_bf16(
                a[mt], bfrag[1][ks], acc[mt][1], 0, 0, 0);
        }
    }

    unsigned short* hrel = h + (size_t)blockIdx.y * n_nodes * OUT;
    #pragma unroll
    for (int mt = 0; mt < 8; ++mt) {
        #pragma unroll
        for (int rg = 0; rg < 4; ++rg) {
            const int row = row0 + mt * 16 + q * 4 + rg;
            if (row < n_nodes) {
                unsigned short* hp = hrel + (size_t)row * OUT + wave * 32 + m;
                hp[0]  = f2bf(acc[mt][0][rg]);
                hp[16] = f2bf(acc[mt][1][rg]);
            }
        }
    }
}

__global__ __launch_bounds__(256) void fill_kernel(
    const int* __restrict__ src, const int* __restrict__ dst,
    const float* __restrict__ vals, int* __restrict__ counts,
    int2* __restrict__ bucket, int4* __restrict__ spill,
    int* __restrict__ spill_cnt, int n_edges, int n_nodes,
    int cap, int spill_max)
{
    const int e = blockIdx.x * 256 + threadIdx.x;
    if (e >= n_edges) return;
    const size_t g = (size_t)blockIdx.y * n_edges + e;
    const int d = dst[g];
    const int enc = blockIdx.y * n_nodes + src[g];
    const int pos = atomicAdd(&counts[d], 1);
    if (pos < cap) {
        bucket[(size_t)d * cap + pos] = make_int2(enc, __float_as_int(vals[g]));
    } else {
        const int sp = atomicAdd(spill_cnt, 1);
        if (sp < spill_max)
            spill[sp] = make_int4(d, enc, __float_as_int(vals[g]), 0);
    }
}

__global__ __launch_bounds__(256) void gather_kernel(
    const unsigned short* __restrict__ h, const int2* __restrict__ bucket,
    const int* __restrict__ counts, float* __restrict__ out,
    int n_nodes, int cap, int accum)
{
    const int node = blockIdx.x * 8 + (threadIdx.x >> 5);
    const int lane = threadIdx.x & 31;
    if (node >= n_nodes) return;
    int cnt = counts[node];
    if (cnt > cap) cnt = cap;
    const int2* __restrict__ b = bucket + (size_t)node * cap;
    float4* __restrict__ op = (float4*)(out + (size_t)node * OUT);

    float4 acc = accum ? op[lane] : make_float4(0.f, 0.f, 0.f, 0.f);
    int j = 0;
    for (; j + 4 <= cnt; j += 4) {
        const int2 r0 = b[j], r1 = b[j + 1], r2 = b[j + 2], r3 = b[j + 3];
        const uint2 h0 = ((const uint2*)(h + (size_t)r0.x * OUT))[lane];
        const uint2 h1 = ((const uint2*)(h + (size_t)r1.x * OUT))[lane];
        const uint2 h2 = ((const uint2*)(h + (size_t)r2.x * OUT))[lane];
        const uint2 h3 = ((const uint2*)(h + (size_t)r3.x * OUT))[lane];
        const float v0 = __int_as_float(r0.y), v1 = __int_as_float(r1.y);
        const float v2 = __int_as_float(r2.y), v3 = __int_as_float(r3.y);
        acc.x += v0*bflo(h0.x) + v1*bflo(h1.x) + v2*bflo(h2.x) + v3*bflo(h3.x);
        acc.y += v0*bfhi(h0.x) + v1*bfhi(h1.x) + v2*bfhi(h2.x) + v3*bfhi(h3.x);
        acc.z += v0*bflo(h0.y) + v1*bflo(h1.y) + v2*bflo(h2.y) + v3*bflo(h3.y);
        acc.w += v0*bfhi(h0.y) + v1*bfhi(h1.y) + v2*bfhi(h2.y) + v3*bfhi(h3.y);
    }
    for (; j < cnt; ++j) {
        const int2 r0 = b[j];
        const float v = __int_as_float(r0.y);
        const uint2 hv = ((const uint2*)(h + (size_t)r0.x * OUT))[lane];
        acc.x += v * bflo(hv.x); acc.y += v * bfhi(hv.x);
        acc.z += v * bflo(hv.y); acc.w += v * bfhi(hv.y);
    }
    op[lane] = acc;
}

__global__ __launch_bounds__(256) void spill_kernel(
    const unsigned short* __restrict__ h, const int4* __restrict__ spill,
    const int* __restrict__ spill_cnt, float* __restrict__ out, int spill_max)
{
    int n = *spill_cnt;
    if (n > spill_max) n = spill_max;
    const int w = (blockIdx.x * 256 + threadIdx.x) >> 6;
    const int lane = threadIdx.x & 63;
    const int nw = gridDim.x * 4;
    for (int i = w; i < n; i += nw) {
        const int4 s = spill[i];
        const float v = __int_as_float(s.z);
        const unsigned int u = ((const unsigned int*)(h + (size_t)s.y * OUT))[lane];
        float* __restrict__ orow = out + (size_t)s.x * OUT;
        __hip_atomic_fetch_add(orow + lane * 2,     v * bflo(u),
                               __ATOMIC_RELAXED, __HIP_MEMORY_SCOPE_AGENT);
        __hip_atomic_fetch_add(orow + lane * 2 + 1, v * bfhi(u),
                               __ATOMIC_RELAXED, __HIP_MEMORY_SCOPE_AGENT);
    }
}

__global__ __launch_bounds__(256) void scatter_kernel(
    const unsigned short* __restrict__ h, const int* __restrict__ src,
    const int* __restrict__ dst, const float* __restrict__ vals,
    float* __restrict__ out, int n_edges)
{
    const int e = blockIdx.x * 8 + (threadIdx.x >> 5);
    if (e >= n_edges) return;
    const int lane = threadIdx.x & 31;
    const int s = src[e];
    const int d = dst[e];
    const float v = vals[e];
    const unsigned int* __restrict__ hrow =
        (const unsigned int*)(h + (size_t)s * OUT);
    float* __restrict__ orow = out + (size_t)d * OUT;
    #pragma unroll
    for (int kk = 0; kk < 2; ++kk) {
        const int jj = lane + kk * 32;
        const unsigned int u = hrow[jj];
        __hip_atomic_fetch_add(orow + jj * 2,     v * bflo(u),
                               __ATOMIC_RELAXED, __HIP_MEMORY_SCOPE_AGENT);
        __hip_atomic_fetch_add(orow + jj * 2 + 1, v * bfhi(u),
                               __ATOMIC_RELAXED, __HIP_MEMORY_SCOPE_AGENT);
    }
}

extern "C" void kernel_launch(void* const* d_in, const int* in_sizes, int n_in,
                              void* d_out, int out_size, void* d_ws, size_t ws_size,
                              hipStream_t stream) {
    const float* inp     = (const float*)d_in[0];
    const int*   src     = (const int*)  d_in[1];
    const int*   dst     = (const int*)  d_in[2];
    const float* vals    = (const float*)d_in[3];
    const float* weights = (const float*)d_in[4];
    float* out = (float*)d_out;

    const int n_nodes = in_sizes[0] / IN;            // 50000
    const int n_rel   = in_sizes[4] / (IN * OUT);    // 8
    const int n_edges = in_sizes[1] / n_rel;         // 100000

    auto align_up = [](size_t x) { return (x + 255) & ~(size_t)255; };
    const int SPILL_MAX = 65536;
    const size_t sz_inpb   = align_up((size_t)n_nodes * IN * 2);
    const size_t sz_wt     = align_up((size_t)n_rel * IN * OUT * 2);
    const size_t sz_spill  = align_up((size_t)SPILL_MAX * 16);

    const int conv_n8 = n_nodes * IN / 8;
    const int wt_tot  = n_rel * IN * OUT;
    const int gemm_gx = (n_nodes + 127) / 128;
    const int gath_gx = (n_nodes + 7) / 8;
    const int fill_gx = (n_edges + 255) / 256;
    const int nbins   = (n_nodes + NPB - 1) / NPB;   // 782

    // ---- primary path: destarved fused fill + per-bin bf16-flush gather GEMM
    if (n_rel <= 8 && n_nodes < (1 << 19) && nbins <= NBINS_MAX) {
        const size_t ncells  = (size_t)n_rel * nbins;
        const size_t sz_bcnt = align_up((ncells + 1) * 4);
        int cap = 0;
        const int caps[] = {256, 192, 128};
        for (int c : caps) {
            const size_t sz_binned = align_up(ncells * c * 8);
            if (sz_inpb + sz_wt + sz_bcnt + sz_spill + sz_binned <= ws_size) {
                cap = c; break;
            }
        }
        if (cap > 0) {
            const size_t sz_binned = align_up(ncells * cap * 8);
            char* p = (char*)d_ws;
            unsigned short* inpb = (unsigned short*)p;  p += sz_inpb;
            unsigned short* wtb  = (unsigned short*)p;  p += sz_wt;
            int*   bin_cnt = (int*)p;   p += sz_bcnt;
            int4*  spill   = (int4*)p;  p += sz_spill;
            int2*  binned  = (int2*)p;  p += sz_binned;
            int*   spill_cnt = bin_cnt + ncells;

            const int nbI = (conv_n8 + 255) / 256;
            const int nbW = (wt_tot + 255) / 256;
            const int fgx = (n_edges + EPB - 1) / EPB;
            const int nF  = fgx * n_rel;

            hipMemsetAsync(bin_cnt, 0, (ncells + 1) * 4, stream);
            prep_kernel<<<nF + nbI + nbW, 256, 0, stream>>>(
                src, dst, vals, bin_cnt, binned, spill, spill_cnt,
                n_edges, n_nodes, nbins, cap, SPILL_MAX, fgx, nF,
                inp, inpb, conv_n8, nbI, weights, wtb, wt_tot);
            bin_gemm_kernel<<<nbins, 256, 0, stream>>>(
                inpb, wtb, binned, bin_cnt, out, n_nodes, nbins, cap, n_rel);
            spill_w_kernel<<<128, 256, 0, stream>>>(
                inpb, wtb, spill, spill_cnt, out, SPILL_MAX);
            return;
        }
    }

    const size_t sz_counts = align_up((size_t)(n_nodes + 1) * 4);
    const size_t fixed = sz_inpb + sz_wt + sz_counts + sz_spill;

    // ---- legacy full path: per-node buckets + h GEMM + gather ----
    {
        const size_t sz_h = (size_t)n_rel * n_nodes * OUT * 2;
        int cap = 0;
        const int caps[] = {64, 48, 32, 24, 20};
        for (int c : caps) {
            if (fixed + sz_h + align_up((size_t)n_nodes * c * 8) <= ws_size) {
                cap = c; break;
            }
        }
        if (cap > 0) {
            char* p = (char*)d_ws;
            unsigned short* inpb = (unsigned short*)p;  p += sz_inpb;
            unsigned short* wtb  = (unsigned short*)p;  p += sz_wt;
            int*   counts = (int*)p;    p += sz_counts;
            int4*  spill  = (int4*)p;   p += sz_spill;
            unsigned short* h = (unsigned short*)p;     p += sz_h;
            int2*  bucket = (int2*)p;
            int*   spill_cnt = counts + n_nodes;

            conv_inp_kernel<<<(conv_n8 + 255) / 256, 256, 0, stream>>>(
                inp, inpb, conv_n8);
            conv_w_kernel<<<(wt_tot + 255) / 256, 256, 0, stream>>>(
                weights, wtb, wt_tot);
            hipMemsetAsync(counts, 0, (size_t)(n_nodes + 1) * 4, stream);
            dim3 fg(fill_gx, n_rel);
            fill_kernel<<<fg, 256, 0, stream>>>(src, dst, vals, counts, bucket,
                                                spill, spill_cnt, n_edges,
                                                n_nodes, cap, SPILL_MAX);
            dim3 gg(gemm_gx, n_rel);
            mfma_gemm<<<gg, 256, 0, stream>>>(inpb, wtb, h, 0, n_nodes);
            gather_kernel<<<gath_gx, 256, 0, stream>>>(h, bucket, counts, out,
                                                       n_nodes, cap, 0);
            spill_kernel<<<128, 256, 0, stream>>>(h, spill, spill_cnt, out,
                                                  SPILL_MAX);
            return;
        }
    }

    // ---- last resort: per-relation gemm + atomic scatter ----
    {
        char* p = (char*)d_ws;
        unsigned short* inpb = (unsigned short*)p;  p += sz_inpb;
        unsigned short* wtb  = (unsigned short*)p;  p += sz_wt;
        unsigned short* h = (unsigned short*)p;

        conv_inp_kernel<<<(conv_n8 + 255) / 256, 256, 0, stream>>>(
            inp, inpb, conv_n8);
        conv_w_kernel<<<(wt_tot + 255) / 256, 256, 0, stream>>>(
            weights, wtb, wt_tot);
        hipMemsetAsync(out, 0, (size_t)n_nodes * OUT * 4, stream);
        const int sgx = (n_edges + 7) / 8;
        for (int r = 0; r < n_rel; ++r) {
            const size_t eoff = (size_t)r * n_edges;
            dim3 gg(gemm_gx, 1);
            mfma_gemm<<<gg, 256, 0, stream>>>(inpb, wtb, h, r, n_nodes);
            scatter_kernel<<<sgx, 256, 0, stream>>>(h, src + eoff, dst + eoff,
                                                    vals + eoff, out, n_edges);
        }
    }
}

// Round 16
// 184.880 us; speedup vs baseline: 1.3001x; 1.0010x over previous
//
#include <hip/hip_runtime.h>

// GCN layer: out = sum_r segment_sum(vals_r * inp[src_r], dst_r) @ W_r
// Round 20 = round-14 structure (verified 185 us; bin_gemm 81.8) with ONE
// parameter change: EPB 2048 -> 1024. Fill blocks 392 -> 784 (~3/CU, was
// 1.5/CU while on the critical path): halves each fill block's serial
// pass lengths and overlaps allocation-atomic latency across more blocks.
// prep (~80 us, = bin_gemm) is the un-attacked half of the budget.
// N=50000, R=8, E=100000, IN=OUT=128.

constexpr int IN  = 128;
constexpr int OUT = 128;
constexpr int LDK = 136;     // legacy bf16 LDS row pad (fallback kernels)
constexpr int NPB = 64;      // nodes per bin
constexpr int LDKB = 136;    // bf16 A-tile row stride (elems), 272 B
constexpr int CAPMAX = 256;  // max entries per (rel,bin) cell (<= blockDim)
constexpr int NBINS_MAX = 1024;
constexpr int EPB = 1024;    // edges per fill block (784 fill blocks)

typedef __attribute__((ext_vector_type(8))) short bf16x8;
typedef __attribute__((ext_vector_type(4))) float f32x4;

__device__ inline unsigned short f2bf(float f) {
    unsigned int u = __float_as_uint(f);
    u += 0x7fffu + ((u >> 16) & 1u);          // RNE
    return (unsigned short)(u >> 16);
}
__device__ inline float bflo(unsigned int u) { return __uint_as_float(u << 16); }
__device__ inline float bfhi(unsigned int u) { return __uint_as_float(u & 0xffff0000u); }
__device__ inline unsigned int pack2bf(float a, float b) {
    return (unsigned)f2bf(a) | ((unsigned)f2bf(b) << 16);
}
// HW packed f32->bf16 (RNE), lo=a hi=b. No builtin on gfx950; asm per guide.
__device__ inline unsigned int cvtpk_bf16(float a, float b) {
    unsigned int r;
    asm("v_cvt_pk_bf16_f32 %0, %1, %2" : "=v"(r) : "v"(a), "v"(b));
    return r;
}

// ---------------- converts (standalone, fallback paths) ---------------------
__global__ __launch_bounds__(256) void conv_inp_kernel(
    const float* __restrict__ x, unsigned short* __restrict__ y, int n8)
{
    const int i = blockIdx.x * 256 + threadIdx.x;
    if (i >= n8) return;
    const float4 a = ((const float4*)x)[i * 2];
    const float4 b = ((const float4*)x)[i * 2 + 1];
    uint4 o;
    o.x = pack2bf(a.x, a.y);
    o.y = pack2bf(a.z, a.w);
    o.z = pack2bf(b.x, b.y);
    o.w = pack2bf(b.z, b.w);
    ((uint4*)y)[i] = o;
}

// Wt[r][n][k] = W[r][k][n], bf16
__global__ __launch_bounds__(256) void conv_w_kernel(
    const float* __restrict__ w, unsigned short* __restrict__ wt, int total)
{
    const int t = blockIdx.x * 256 + threadIdx.x;
    if (t >= total) return;
    const int r = t >> 14, rem = t & 16383;
    const int n = rem >> 7, k = rem & 127;
    wt[t] = f2bf(w[(r << 14) + (k << 7) + n]);
}

// ---------------- prep: fill blocks FIRST, then conv blocks -----------------
// Fill: 1024 edges of one relation per block. LDS histogram by bin, one
// global atomicAdd per non-empty bin, place at gbase+localpos.
// entry: .x = ((dst&63)<<19) | src   (needs n_nodes < 2^19)
__global__ __launch_bounds__(256) void prep_kernel(
    const int* __restrict__ src, const int* __restrict__ dst,
    const float* __restrict__ vals, int* __restrict__ bin_cnt,
    int2* __restrict__ binned, int4* __restrict__ spill,
    int* __restrict__ spill_cnt,
    int n_edges, int n_nodes, int nbins, int cap, int spill_max,
    int fgx, int nF,
    const float* __restrict__ x, unsigned short* __restrict__ y, int n8, int nbI,
    const float* __restrict__ w, unsigned short* __restrict__ wtb, int wtot)
{
    __shared__ int hist[NBINS_MAX];
    __shared__ int gbase[NBINS_MAX];

    const int bid = blockIdx.x;
    const int tid = threadIdx.x;

    if (bid >= nF) {
        const int cb = bid - nF;
        if (cb < nbI) {
            const int i = cb * 256 + tid;
            if (i >= n8) return;
            const float4 a = ((const float4*)x)[i * 2];
            const float4 b = ((const float4*)x)[i * 2 + 1];
            uint4 o;
            o.x = pack2bf(a.x, a.y);
            o.y = pack2bf(a.z, a.w);
            o.z = pack2bf(b.x, b.y);
            o.w = pack2bf(b.z, b.w);
            ((uint4*)y)[i] = o;
        } else {
            const int t = (cb - nbI) * 256 + tid;
            if (t >= wtot) return;
            const int r = t >> 14, rem = t & 16383;
            const int n = rem >> 7, k = rem & 127;
            wtb[t] = f2bf(w[(r << 14) + (k << 7) + n]);
        }
        return;
    }

    // ---- fill ----
    const int rel = bid / fgx;
    const int e0 = (bid - rel * fgx) * EPB;
    const size_t base_e = (size_t)rel * n_edges;

    for (int b = tid; b < nbins; b += 256) hist[b] = 0;
    __syncthreads();

    // pass 1: count
    #pragma unroll
    for (int j = 0; j < EPB / 256; ++j) {
        const int e = e0 + j * 256 + tid;
        if (e < n_edges) atomicAdd(&hist[dst[base_e + e] >> 6], 1);
    }
    __syncthreads();

    // allocate one global range per non-empty bin; reset hist for pass 2
    for (int b = tid; b < nbins; b += 256) {
        const int c = hist[b];
        gbase[b] = c ? atomicAdd(&bin_cnt[rel * nbins + b], c) : 0;
        hist[b] = 0;
    }
    __syncthreads();

    // pass 2: place (edge reads L2-hot)
    #pragma unroll
    for (int j = 0; j < EPB / 256; ++j) {
        const int e = e0 + j * 256 + tid;
        if (e >= n_edges) continue;
        const int d = dst[base_e + e];
        const int s = src[base_e + e];
        const float v = vals[base_e + e];
        const int b = d >> 6;
        const int lp = atomicAdd(&hist[b], 1);
        const int pos = gbase[b] + lp;
        if (pos < cap) {
            binned[(size_t)(rel * nbins + b) * cap + pos] =
                make_int2(((d & 63) << 19) | s, __float_as_int(v));
        } else {
            const int sp = atomicAdd(spill_cnt, 1);
            if (sp < spill_max)
                spill[sp] = make_int4(d, (rel << 19) | s, __float_as_int(v), 0);
        }
    }
}

// ---------------- per-bin: reg-held sort + bf16-flush gather + MFMA ---------
__global__ __launch_bounds__(256, 4) void bin_gemm_kernel(
    const unsigned short* __restrict__ inpb,
    const unsigned short* __restrict__ wt,
    const int2* __restrict__ binned, const int* __restrict__ bin_cnt,
    float* __restrict__ out, int n_nodes, int nbins, int cap, int n_rel)
{
    __shared__ unsigned short Ab[NPB * LDKB];   // 17.4 KB bf16 A-tile
    __shared__ int2 sorted[CAPMAX];             // 2 KB
    __shared__ int lcnt[NPB];
    __shared__ int loff[NPB + 1];
    __shared__ int lcur[NPB];
    __shared__ int relcnt[8];

    const int bin = blockIdx.x;
    const int tid = threadIdx.x;
    const int wave = tid >> 6, lane = tid & 63;
    const int m = lane & 15, q = lane >> 4;

    if (tid < n_rel) {
        int c = bin_cnt[tid * nbins + bin];
        relcnt[tid] = c > cap ? cap : c;
    }
    if (tid < NPB) { lcnt[tid] = 0; lcur[tid] = 0; }
    __syncthreads();

    int2 ecur = make_int2((NPB - 1) << 19, 0);
    if (tid < relcnt[0])
        ecur = binned[(size_t)bin * cap + tid];

    f32x4 acc[4][2];
    #pragma unroll
    for (int mt = 0; mt < 4; ++mt) {
        acc[mt][0] = (f32x4){0.f, 0.f, 0.f, 0.f};
        acc[mt][1] = (f32x4){0.f, 0.f, 0.f, 0.f};
    }

    for (int r = 0; r < n_rel; ++r) {
        const int cnt = relcnt[r];

        // W-frag loads issued early: sort+gather hides their L2 latency.
        const unsigned short* wtr = wt + ((size_t)r * OUT + wave * 32) * IN;
        bf16x8 bfrag[2][4];
        #pragma unroll
        for (int nt = 0; nt < 2; ++nt)
            #pragma unroll
            for (int ks = 0; ks < 4; ++ks)
                bfrag[nt][ks] = *(const bf16x8*)(
                    wtr + (size_t)(nt * 16 + m) * IN + ks * 32 + q * 8);

        // R1: zero Ab (linear, conflict-free) + histogram from register
        {
            uint4* A4 = (uint4*)Ab;
            #pragma unroll
            for (int j = 0; j < (NPB * LDKB / 8 + 255) / 256; ++j) {
                const int idx = j * 256 + tid;
                if (idx < NPB * LDKB / 8)
                    A4[idx] = make_uint4(0u, 0u, 0u, 0u);
            }
        }
        if (tid < cnt) atomicAdd(&lcnt[(ecur.x >> 19) & (NPB - 1)], 1);
        __syncthreads();

        // R2: exclusive scan over 64 groups (wave 0)
        if (tid < NPB) {
            const int v = lcnt[tid];
            int incl = v;
            #pragma unroll
            for (int off = 1; off < NPB; off <<= 1) {
                const int t = __shfl_up(incl, off, NPB);
                if (tid >= off) incl += t;
            }
            loff[tid] = incl - v;
            if (tid == NPB - 1) loff[NPB] = incl;
        }
        __syncthreads();

        // R3: place (entry from register); re-zero lcnt for next rel
        if (tid < cnt) {
            const int g = (ecur.x >> 19) & (NPB - 1);
            const int pos = atomicAdd(&lcur[g], 1);
            sorted[loff[g] + pos] = ecur;
        }
        if (tid < NPB) lcnt[tid] = 0;
        __syncthreads();

        // R4: prefetch next rel's entry; sorted-order gather with DIRECT
        // bf16 flush (v_cvt_pk_bf16_f32, 1 instr)
        int2 enext = make_int2((NPB - 1) << 19, 0);
        if (r + 1 < n_rel && tid < relcnt[r + 1])
            enext = binned[(size_t)((r + 1) * nbins + bin) * cap + tid];

        {
            const int g0 = wave * 16;                // 16 nodes per wave
            const int gend = g0 + 15;
            const int start = loff[g0];
            const int end = loff[g0 + 16];
            int cur = g0;
            float a0 = 0.f, a1 = 0.f;
            for (int i = start; i < end; i += 8) {
                int2 e[8]; unsigned int u[8];
                #pragma unroll
                for (int k = 0; k < 8; ++k) {
                    const int idx = i + k;
                    // dummy = wave's LAST node, v=0: overwrite-safe.
                    e[k] = (idx < end) ? sorted[idx]
                                       : make_int2(gend << 19, 0);
                }
                #pragma unroll
                for (int k = 0; k < 8; ++k)
                    u[k] = ((const unsigned int*)(
                        inpb + (size_t)(e[k].x & 0x7ffff) * IN))[lane];
                #pragma unroll
                for (int k = 0; k < 8; ++k) {
                    const int ln = (e[k].x >> 19) & 63;
                    if (ln != cur) {
                        *(unsigned int*)&Ab[cur * LDKB + lane * 2] =
                            cvtpk_bf16(a0, a1);
                        a0 = 0.f; a1 = 0.f; cur = ln;
                    }
                    const float v = __int_as_float(e[k].y);
                    a0 += v * bflo(u[k]); a1 += v * bfhi(u[k]);
                }
            }
            *(unsigned int*)&Ab[cur * LDKB + lane * 2] = cvtpk_bf16(a0, a1);
        }
        if (tid < NPB) lcur[tid] = 0;
        __syncthreads();

        // R5: MFMA — a-frags read directly as bf16x8 from Ab
        #pragma unroll
        for (int ks = 0; ks < 4; ++ks) {
            bf16x8 a[4];
            #pragma unroll
            for (int mt = 0; mt < 4; ++mt)
                a[mt] = *(const bf16x8*)&Ab[(mt * 16 + m) * LDKB
                                            + ks * 32 + q * 8];
            #pragma unroll
            for (int mt = 0; mt < 4; ++mt) {
                acc[mt][0] = __builtin_amdgcn_mfma_f32_16x16x32_bf16(
                    a[mt], bfrag[0][ks], acc[mt][0], 0, 0, 0);
                acc[mt][1] = __builtin_amdgcn_mfma_f32_16x16x32_bf16(
                    a[mt], bfrag[1][ks], acc[mt][1], 0, 0, 0);
            }
        }
        ecur = enext;
        __syncthreads();   // Ab reads done before next rel's zero
    }

    // epilogue
    const int row0 = bin * NPB;
    #pragma unroll
    for (int mt = 0; mt < 4; ++mt) {
        #pragma unroll
        for (int rg = 0; rg < 4; ++rg) {
            const int row = row0 + mt * 16 + q * 4 + rg;
            if (row < n_nodes) {
                float* op = out + (size_t)row * OUT + wave * 32 + m;
                op[0]  = acc[mt][0][rg];
                op[16] = acc[mt][1][rg];
            }
        }
    }
}

// ---------------- spill cleanup: out[d] += val * (inp[src] @ W[rel]) --------
__global__ __launch_bounds__(256) void spill_w_kernel(
    const unsigned short* __restrict__ inpb,
    const unsigned short* __restrict__ wt,
    const int4* __restrict__ spill, const int* __restrict__ spill_cnt,
    float* __restrict__ out, int spill_max)
{
    int n = *spill_cnt;
    if (n > spill_max) n = spill_max;
    const int w = (blockIdx.x * 256 + threadIdx.x) >> 6;
    const int lane = threadIdx.x & 63;
    const int nw = gridDim.x * 4;
    for (int i = w; i < n; i += nw) {
        const int4 s = spill[i];
        const int d = s.x;
        const int rel = s.y >> 19, srcrow = s.y & 0x7ffff;
        const float v = __int_as_float(s.z);
        const unsigned short* irow = inpb + (size_t)srcrow * IN;
        #pragma unroll
        for (int cc = 0; cc < 2; ++cc) {
            const int col = lane * 2 + cc;
            const unsigned short* wrow = wt + ((size_t)rel * OUT + col) * IN;
            float acc = 0.f;
            for (int k8 = 0; k8 < IN; k8 += 8) {
                const uint4 iw = *(const uint4*)(irow + k8);
                const uint4 ww = *(const uint4*)(wrow + k8);
                acc += bflo(iw.x)*bflo(ww.x) + bfhi(iw.x)*bfhi(ww.x)
                     + bflo(iw.y)*bflo(ww.y) + bfhi(iw.y)*bfhi(ww.y)
                     + bflo(iw.z)*bflo(ww.z) + bfhi(iw.z)*bfhi(ww.z)
                     + bflo(iw.w)*bflo(ww.w) + bfhi(iw.w)*bfhi(ww.w);
            }
            __hip_atomic_fetch_add(out + (size_t)d * OUT + col, v * acc,
                                   __ATOMIC_RELAXED, __HIP_MEMORY_SCOPE_AGENT);
        }
    }
}

// ================= legacy fallback machinery (h-based) ======================
__global__ __launch_bounds__(256) void mfma_gemm(
    const unsigned short* __restrict__ inpb,
    const unsigned short* __restrict__ wt,
    unsigned short* __restrict__ h, int rel_base, int n_nodes)
{
    __shared__ unsigned short As[128 * LDK];

    const int rel = rel_base + blockIdx.y;
    const int row0 = blockIdx.x * 128;
    const int tid = threadIdx.x;
    const int wave = tid >> 6, lane = tid & 63;
    const int m = lane & 15, q = lane >> 4;

    {
        const int r = tid >> 1;
        const int half = (tid & 1) * 64;
        const int grow = row0 + r;
        const uint4* gp = (const uint4*)(inpb + (size_t)grow * IN + half);
        uint4* lp = (uint4*)&As[r * LDK + half];
        #pragma unroll
        for (int i = 0; i < 8; ++i) {
            uint4 v = make_uint4(0u, 0u, 0u, 0u);
            if (grow < n_nodes) v = gp[i];
            lp[i] = v;
        }
    }

    bf16x8 bfrag[2][4];
    {
        const unsigned short* wtr = wt + ((size_t)rel * OUT + wave * 32) * IN;
        #pragma unroll
        for (int nt = 0; nt < 2; ++nt)
            #pragma unroll
            for (int ks = 0; ks < 4; ++ks)
                bfrag[nt][ks] = *(const bf16x8*)(
                    wtr + (size_t)(nt * 16 + m) * IN + ks * 32 + q * 8);
    }

    __syncthreads();

    f32x4 acc[8][2];
    #pragma unroll
    for (int mt = 0; mt < 8; ++mt)
        #pragma unroll
        for (int nt = 0; nt < 2; ++nt)
            acc[mt][nt] = (f32x4){0.f, 0.f, 0.f, 0.f};

    #pragma unroll
    for (int ks = 0; ks < 4; ++ks) {
        bf16x8 a[8];
        #pragma unroll
        for (int mt = 0; mt < 8; ++mt)
            a[mt] = *(const bf16x8*)&As[(mt * 16 + m) * LDK + ks * 32 + q * 8];
        #pragma unroll
        for (int mt = 0; mt < 8; ++mt) {
            acc[mt][0] = __builtin_amdgcn_mfma_f32_16x16x32_bf16(
                a[mt], bfrag[0][ks], acc[mt][0], 0, 0, 0);
            acc[mt][1] = __builtin_amdgcn_mfma_f32_16x16x32_bf16(
                a[mt], bfrag[1][ks], acc[mt][1], 0, 0, 0);
        }
    }

    unsigned short* hrel = h + (size_t)blockIdx.y * n_nodes * OUT;
    #pragma unroll
    for (int mt = 0; mt < 8; ++mt) {
        #pragma unroll
        for (int rg = 0; rg < 4; ++rg) {
            const int row = row0 + mt * 16 + q * 4 + rg;
            if (row < n_nodes) {
                unsigned short* hp = hrel + (size_t)row * OUT + wave * 32 + m;
                hp[0]  = f2bf(acc[mt][0][rg]);
                hp[16] = f2bf(acc[mt][1][rg]);
            }
        }
    }
}

__global__ __launch_bounds__(256) void fill_kernel(
    const int* __restrict__ src, const int* __restrict__ dst,
    const float* __restrict__ vals, int* __restrict__ counts,
    int2* __restrict__ bucket, int4* __restrict__ spill,
    int* __restrict__ spill_cnt, int n_edges, int n_nodes,
    int cap, int spill_max)
{
    const int e = blockIdx.x * 256 + threadIdx.x;
    if (e >= n_edges) return;
    const size_t g = (size_t)blockIdx.y * n_edges + e;
    const int d = dst[g];
    const int enc = blockIdx.y * n_nodes + src[g];
    const int pos = atomicAdd(&counts[d], 1);
    if (pos < cap) {
        bucket[(size_t)d * cap + pos] = make_int2(enc, __float_as_int(vals[g]));
    } else {
        const int sp = atomicAdd(spill_cnt, 1);
        if (sp < spill_max)
            spill[sp] = make_int4(d, enc, __float_as_int(vals[g]), 0);
    }
}

__global__ __launch_bounds__(256) void gather_kernel(
    const unsigned short* __restrict__ h, const int2* __restrict__ bucket,
    const int* __restrict__ counts, float* __restrict__ out,
    int n_nodes, int cap, int accum)
{
    const int node = blockIdx.x * 8 + (threadIdx.x >> 5);
    const int lane = threadIdx.x & 31;
    if (node >= n_nodes) return;
    int cnt = counts[node];
    if (cnt > cap) cnt = cap;
    const int2* __restrict__ b = bucket + (size_t)node * cap;
    float4* __restrict__ op = (float4*)(out + (size_t)node * OUT);

    float4 acc = accum ? op[lane] : make_float4(0.f, 0.f, 0.f, 0.f);
    int j = 0;
    for (; j + 4 <= cnt; j += 4) {
        const int2 r0 = b[j], r1 = b[j + 1], r2 = b[j + 2], r3 = b[j + 3];
        const uint2 h0 = ((const uint2*)(h + (size_t)r0.x * OUT))[lane];
        const uint2 h1 = ((const uint2*)(h + (size_t)r1.x * OUT))[lane];
        const uint2 h2 = ((const uint2*)(h + (size_t)r2.x * OUT))[lane];
        const uint2 h3 = ((const uint2*)(h + (size_t)r3.x * OUT))[lane];
        const float v0 = __int_as_float(r0.y), v1 = __int_as_float(r1.y);
        const float v2 = __int_as_float(r2.y), v3 = __int_as_float(r3.y);
        acc.x += v0*bflo(h0.x) + v1*bflo(h1.x) + v2*bflo(h2.x) + v3*bflo(h3.x);
        acc.y += v0*bfhi(h0.x) + v1*bfhi(h1.x) + v2*bfhi(h2.x) + v3*bfhi(h3.x);
        acc.z += v0*bflo(h0.y) + v1*bflo(h1.y) + v2*bflo(h2.y) + v3*bflo(h3.y);
        acc.w += v0*bfhi(h0.y) + v1*bfhi(h1.y) + v2*bfhi(h2.y) + v3*bfhi(h3.y);
    }
    for (; j < cnt; ++j) {
        const int2 r0 = b[j];
        const float v = __int_as_float(r0.y);
        const uint2 hv = ((const uint2*)(h + (size_t)r0.x * OUT))[lane];
        acc.x += v * bflo(hv.x); acc.y += v * bfhi(hv.x);
        acc.z += v * bflo(hv.y); acc.w += v * bfhi(hv.y);
    }
    op[lane] = acc;
}

__global__ __launch_bounds__(256) void spill_kernel(
    const unsigned short* __restrict__ h, const int4* __restrict__ spill,
    const int* __restrict__ spill_cnt, float* __restrict__ out, int spill_max)
{
    int n = *spill_cnt;
    if (n > spill_max) n = spill_max;
    const int w = (blockIdx.x * 256 + threadIdx.x) >> 6;
    const int lane = threadIdx.x & 63;
    const int nw = gridDim.x * 4;
    for (int i = w; i < n; i += nw) {
        const int4 s = spill[i];
        const float v = __int_as_float(s.z);
        const unsigned int u = ((const unsigned int*)(h + (size_t)s.y * OUT))[lane];
        float* __restrict__ orow = out + (size_t)s.x * OUT;
        __hip_atomic_fetch_add(orow + lane * 2,     v * bflo(u),
                               __ATOMIC_RELAXED, __HIP_MEMORY_SCOPE_AGENT);
        __hip_atomic_fetch_add(orow + lane * 2 + 1, v * bfhi(u),
                               __ATOMIC_RELAXED, __HIP_MEMORY_SCOPE_AGENT);
    }
}

__global__ __launch_bounds__(256) void scatter_kernel(
    const unsigned short* __restrict__ h, const int* __restrict__ src,
    const int* __restrict__ dst, const float* __restrict__ vals,
    float* __restrict__ out, int n_edges)
{
    const int e = blockIdx.x * 8 + (threadIdx.x >> 5);
    if (e >= n_edges) return;
    const int lane = threadIdx.x & 31;
    const int s = src[e];
    const int d = dst[e];
    const float v = vals[e];
    const unsigned int* __restrict__ hrow =
        (const unsigned int*)(h + (size_t)s * OUT);
    float* __restrict__ orow = out + (size_t)d * OUT;
    #pragma unroll
    for (int kk = 0; kk < 2; ++kk) {
        const int jj = lane + kk * 32;
        const unsigned int u = hrow[jj];
        __hip_atomic_fetch_add(orow + jj * 2,     v * bflo(u),
                               __ATOMIC_RELAXED, __HIP_MEMORY_SCOPE_AGENT);
        __hip_atomic_fetch_add(orow + jj * 2 + 1, v * bfhi(u),
                               __ATOMIC_RELAXED, __HIP_MEMORY_SCOPE_AGENT);
    }
}

extern "C" void kernel_launch(void* const* d_in, const int* in_sizes, int n_in,
                              void* d_out, int out_size, void* d_ws, size_t ws_size,
                              hipStream_t stream) {
    const float* inp     = (const float*)d_in[0];
    const int*   src     = (const int*)  d_in[1];
    const int*   dst     = (const int*)  d_in[2];
    const float* vals    = (const float*)d_in[3];
    const float* weights = (const float*)d_in[4];
    float* out = (float*)d_out;

    const int n_nodes = in_sizes[0] / IN;            // 50000
    const int n_rel   = in_sizes[4] / (IN * OUT);    // 8
    const int n_edges = in_sizes[1] / n_rel;         // 100000

    auto align_up = [](size_t x) { return (x + 255) & ~(size_t)255; };
    const int SPILL_MAX = 65536;
    const size_t sz_inpb   = align_up((size_t)n_nodes * IN * 2);
    const size_t sz_wt     = align_up((size_t)n_rel * IN * OUT * 2);
    const size_t sz_spill  = align_up((size_t)SPILL_MAX * 16);

    const int conv_n8 = n_nodes * IN / 8;
    const int wt_tot  = n_rel * IN * OUT;
    const int gemm_gx = (n_nodes + 127) / 128;
    const int gath_gx = (n_nodes + 7) / 8;
    const int fill_gx = (n_edges + 255) / 256;
    const int nbins   = (n_nodes + NPB - 1) / NPB;   // 782

    // ---- primary path: destarved fused fill + per-bin bf16-flush gather GEMM
    if (n_rel <= 8 && n_nodes < (1 << 19) && nbins <= NBINS_MAX) {
        const size_t ncells  = (size_t)n_rel * nbins;
        const size_t sz_bcnt = align_up((ncells + 1) * 4);
        int cap = 0;
        const int caps[] = {256, 192, 128};
        for (int c : caps) {
            const size_t sz_binned = align_up(ncells * c * 8);
            if (sz_inpb + sz_wt + sz_bcnt + sz_spill + sz_binned <= ws_size) {
                cap = c; break;
            }
        }
        if (cap > 0) {
            const size_t sz_binned = align_up(ncells * cap * 8);
            char* p = (char*)d_ws;
            unsigned short* inpb = (unsigned short*)p;  p += sz_inpb;
            unsigned short* wtb  = (unsigned short*)p;  p += sz_wt;
            int*   bin_cnt = (int*)p;   p += sz_bcnt;
            int4*  spill   = (int4*)p;  p += sz_spill;
            int2*  binned  = (int2*)p;  p += sz_binned;
            int*   spill_cnt = bin_cnt + ncells;

            const int nbI = (conv_n8 + 255) / 256;
            const int nbW = (wt_tot + 255) / 256;
            const int fgx = (n_edges + EPB - 1) / EPB;
            const int nF  = fgx * n_rel;

            hipMemsetAsync(bin_cnt, 0, (ncells + 1) * 4, stream);
            prep_kernel<<<nF + nbI + nbW, 256, 0, stream>>>(
                src, dst, vals, bin_cnt, binned, spill, spill_cnt,
                n_edges, n_nodes, nbins, cap, SPILL_MAX, fgx, nF,
                inp, inpb, conv_n8, nbI, weights, wtb, wt_tot);
            bin_gemm_kernel<<<nbins, 256, 0, stream>>>(
                inpb, wtb, binned, bin_cnt, out, n_nodes, nbins, cap, n_rel);
            spill_w_kernel<<<128, 256, 0, stream>>>(
                inpb, wtb, spill, spill_cnt, out, SPILL_MAX);
            return;
        }
    }

    const size_t sz_counts = align_up((size_t)(n_nodes + 1) * 4);
    const size_t fixed = sz_inpb + sz_wt + sz_counts + sz_spill;

    // ---- legacy full path: per-node buckets + h GEMM + gather ----
    {
        const size_t sz_h = (size_t)n_rel * n_nodes * OUT * 2;
        int cap = 0;
        const int caps[] = {64, 48, 32, 24, 20};
        for (int c : caps) {
            if (fixed + sz_h + align_up((size_t)n_nodes * c * 8) <= ws_size) {
                cap = c; break;
            }
        }
        if (cap > 0) {
            char* p = (char*)d_ws;
            unsigned short* inpb = (unsigned short*)p;  p += sz_inpb;
            unsigned short* wtb  = (unsigned short*)p;  p += sz_wt;
            int*   counts = (int*)p;    p += sz_counts;
            int4*  spill  = (int4*)p;   p += sz_spill;
            unsigned short* h = (unsigned short*)p;     p += sz_h;
            int2*  bucket = (int2*)p;
            int*   spill_cnt = counts + n_nodes;

            conv_inp_kernel<<<(conv_n8 + 255) / 256, 256, 0, stream>>>(
                inp, inpb, conv_n8);
            conv_w_kernel<<<(wt_tot + 255) / 256, 256, 0, stream>>>(
                weights, wtb, wt_tot);
            hipMemsetAsync(counts, 0, (size_t)(n_nodes + 1) * 4, stream);
            dim3 fg(fill_gx, n_rel);
            fill_kernel<<<fg, 256, 0, stream>>>(src, dst, vals, counts, bucket,
                                                spill, spill_cnt, n_edges,
                                                n_nodes, cap, SPILL_MAX);
            dim3 gg(gemm_gx, n_rel);
            mfma_gemm<<<gg, 256, 0, stream>>>(inpb, wtb, h, 0, n_nodes);
            gather_kernel<<<gath_gx, 256, 0, stream>>>(h, bucket, counts, out,
                                                       n_nodes, cap, 0);
            spill_kernel<<<128, 256, 0, stream>>>(h, spill, spill_cnt, out,
                                                  SPILL_MAX);
            return;
        }
    }

    // ---- last resort: per-relation gemm + atomic scatter ----
    {
        char* p = (char*)d_ws;
        unsigned short* inpb = (unsigned short*)p;  p += sz_inpb;
        unsigned short* wtb  = (unsigned short*)p;  p += sz_wt;
        unsigned short* h = (unsigned short*)p;

        conv_inp_kernel<<<(conv_n8 + 255) / 256, 256, 0, stream>>>(
            inp, inpb, conv_n8);
        conv_w_kernel<<<(wt_tot + 255) / 256, 256, 0, stream>>>(
            weights, wtb, wt_tot);
        hipMemsetAsync(out, 0, (size_t)n_nodes * OUT * 4, stream);
        const int sgx = (n_edges + 7) / 8;
        for (int r = 0; r < n_rel; ++r) {
            const size_t eoff = (size_t)r * n_edges;
            dim3 gg(gemm_gx, 1);
            mfma_gemm<<<gg, 256, 0, stream>>>(inpb, wtb, h, r, n_nodes);
            scatter_kernel<<<sgx, 256, 0, stream>>>(h, src + eoff, dst + eoff,
                                                    vals + eoff, out, n_edges);
        }
    }
}